// Round 7
// baseline (2737.102 us; speedup 1.0000x reference)
//
#include <hip/hip_runtime.h>
#include <stdint.h>

#define TT 2560
#define BB 64
#define CC 22

typedef unsigned short ushort_t;
typedef __attribute__((ext_vector_type(4))) float floatx4;
typedef __attribute__((ext_vector_type(8))) short bf16x8;
typedef __attribute__((ext_vector_type(4))) int intx4;

__device__ __forceinline__ float bf2f(ushort_t u){
  union { uint32_t i; float f; } v; v.i = ((uint32_t)u) << 16; return v.f;
}
__device__ __forceinline__ ushort_t f2bf(float f){
  union { float f; uint32_t i; } v; v.f = f;
  uint32_t r = v.i + 0x7FFFu + ((v.i >> 16) & 1u);
  return (ushort_t)(r >> 16);
}
__device__ __forceinline__ float fsig(float x){ return 1.f/(1.f + __expf(-x)); }
__device__ __forceinline__ float ftanh(float x){ return 2.f/(1.f + __expf(-2.f*x)) - 1.f; }

// LDS-only barrier: does NOT drain vmcnt; global stores/prefetch loads stay in
// flight across the 2560-step serial loop.
__device__ __forceinline__ void ldsbar(){
  asm volatile("s_waitcnt lgkmcnt(0)\n\ts_barrier" ::: "memory");
}
// Same-wave LDS ordering fence (no barrier): drain DS queue, forbid reordering.
__device__ __forceinline__ void ldsfence(){
  asm volatile("s_waitcnt lgkmcnt(0)" ::: "memory");
}

// ---------------- K0a: cast x [B][C][T] fp32 -> xc [B][C][T] bf16 (time-contiguous)
__global__ __launch_bounds__(256) void k_convert_x(const float* __restrict__ x, ushort_t* __restrict__ xc){
  int i4 = blockIdx.x*256 + threadIdx.x;
  if (i4 >= BB*CC*TT/4) return;
  const float4 v = ((const float4*)x)[i4];
  uint2 o;
  o.x = (uint32_t)f2bf(v.x) | ((uint32_t)f2bf(v.y) << 16);
  o.y = (uint32_t)f2bf(v.z) | ((uint32_t)f2bf(v.w) << 16);
  ((uint2*)xc)[i4] = o;
}

// ---------------- K0a2: pack x into MFMA A-fragment order.
__global__ __launch_bounds__(256) void k_prep_xa(const ushort_t* __restrict__ xc, ushort_t* __restrict__ xA){
  int idx = blockIdx.x*256 + threadIdx.x;          // (cb*TT + t)*16 + l16
  if (idx >= 16*TT*16) return;
  int l16 = idx & 15;
  int rest = idx >> 4;
  int t = rest % TT, cb = rest / TT;
  int c4 = l16 >> 2, q = l16 & 3;
  int b = cb*4 + c4;
  ushort_t v[8];
  #pragma unroll
  for (int j=0;j<8;j++){
    int c = q*8 + j;
    v[j] = (c < CC) ? xc[((size_t)b*CC + c)*TT + t] : (ushort_t)0;
  }
  *(uint4*)(xA + (size_t)idx*8) = *(const uint4*)v;
}

// ---------------- K0w: per-tensor absmax of the 4 recurrent weight matrices.
__global__ __launch_bounds__(256) void k_wmax(const float* __restrict__ w0f, const float* __restrict__ w0b,
                                              const float* __restrict__ w1f, const float* __restrict__ w1b,
                                              float* __restrict__ scl){
  const int b = blockIdx.x;
  const float* W = (b==0) ? w0f : (b==1) ? w0b : (b==2) ? w1f : w1b;
  const int n = (b < 2) ? 128*512 : 64*256;
  float mx = 0.f;
  for (int i = threadIdx.x; i < n; i += 256) mx = fmaxf(mx, fabsf(W[i]));
  __shared__ float red[256];
  red[threadIdx.x] = mx;
  __syncthreads();
  for (int s = 128; s > 0; s >>= 1){
    if (threadIdx.x < s) red[threadIdx.x] = fmaxf(red[threadIdx.x], red[threadIdx.x+s]);
    __syncthreads();
  }
  if (threadIdx.x == 0) scl[b] = fmaxf(red[0], 1e-8f);
}

// ---------------- K0b: layer-0 weights.
// W0Q[dir][n=512][k=128] int8 = round(Wh[k][n] * 127/sw); B0X[dir][n=512][k=32] bf16 x-part.
__global__ __launch_bounds__(256) void k_prep_l0(const float* __restrict__ WxF, const float* __restrict__ WhF,
                                                 const float* __restrict__ WxB, const float* __restrict__ WhB,
                                                 const float* __restrict__ scl,
                                                 char* __restrict__ W0Q, ushort_t* __restrict__ B0X){
  int idx = blockIdx.x*256 + threadIdx.x;
  if (idx >= 2*512*160) return;
  int dir = idx / 81920; int r = idx % 81920; int n = r / 160; int k = r % 160;
  if (k < 128){
    const float* Wh = dir ? WhB : WhF;
    float sw = scl[dir];
    W0Q[(size_t)dir*65536 + n*128 + k] = (char)(int)rintf(Wh[k*512 + n] * (127.f/sw));
  } else {
    const float* Wx = dir ? WxB : WxF;
    int kx = k - 128;
    float v = (kx < CC) ? Wx[kx*512 + n] : 0.f;
    B0X[(size_t)dir*16384 + n*32 + kx] = f2bf(v);
  }
}

// ---------------- K0c: W1Q[dir][n=256][k=64] int8 = round(Wh1[k][n] * 127/sw)
__global__ __launch_bounds__(256) void k_prep_l1(const float* __restrict__ WhF, const float* __restrict__ WhB,
                                                 const float* __restrict__ scl,
                                                 char* __restrict__ W1Q){
  int idx = blockIdx.x*256 + threadIdx.x;
  if (idx >= 2*256*64) return;
  int dir = idx >> 14; int r = idx & 16383; int n = r >> 6; int k = r & 63;
  const float* Wh = dir ? WhB : WhF;
  float sw = scl[2+dir];
  W1Q[(size_t)dir*16384 + n*64 + k] = (char)(int)rintf(Wh[k*256 + n] * (127.f/sw));
}

// ---------------- K0d: WT[dir][n=256][k=256] = Wx1[k][n]  (for xz1 gemm)
__global__ __launch_bounds__(256) void k_prep_wxT(const float* __restrict__ Wf, const float* __restrict__ Wb,
                                                  ushort_t* __restrict__ WT){
  int idx = blockIdx.x*256 + threadIdx.x;
  int dir = idx >> 16; int r = idx & 65535; int n = r >> 8; int k = r & 255;
  const float* W = dir ? Wb : Wf;
  WT[idx] = f2bf(W[k*256 + n]);
}

// ---------------- K1: layer-0 scan, int8 recurrence (r6-proven, unchanged).
__global__ __launch_bounds__(512, 2) void k_lstm0m(
  const ushort_t* __restrict__ xA, const char* __restrict__ W0Q,
  const ushort_t* __restrict__ B0X, const float* __restrict__ scl,
  const float* __restrict__ bF, const float* __restrict__ bB,
  ushort_t* __restrict__ h0seq)                     // [B][T][256]: fwd 0..127, bwd 128..255
{
  const int dir = blockIdx.x & 1, cb = blockIdx.x >> 1;   // cb 0..15
  const int tid = threadIdx.x;
  const int wv = tid >> 6, lane = tid & 63, m = lane & 15, q = lane >> 4;
  const int u = wv*16 + m;                                // unit 0..127
  const float* bi = dir ? bB : bF;
  const float sclc = scl[dir] * (1.f/16129.f);            // sw/(127*127)

  __shared__ __align__(16) char AbufC[2][4][144];

  bf16x8 Bfx[4];
  intx4  BfQ[4][2];
  {
    const ushort_t* Bx = B0X + (size_t)dir*16384;
    const char*     Bq = W0Q + (size_t)dir*65536;
    #pragma unroll
    for (int g=0; g<4; g++){
      int nrow = (g*8 + wv)*16 + m;
      Bfx[g] = *(const bf16x8*)(Bx + (size_t)nrow*32 + q*8);
      #pragma unroll
      for (int kt=0; kt<2; kt++)
        BfQ[g][kt] = *(const intx4*)(Bq + (size_t)nrow*128 + kt*64 + q*16);
    }
  }
  float bz[4];
  #pragma unroll
  for (int g=0; g<4; g++) bz[g] = bi[g*128 + u];

  if (tid < (int)(sizeof(AbufC)/4)) ((uint32_t*)AbufC)[tid] = 0u;

  const ushort_t* xap = xA + (((size_t)cb*TT)*16 + (size_t)((m>>2)*4 + q))*8;
  uint4 px[4];
  #pragma unroll
  for (int j=0; j<4; j++){
    int tj = dir ? (TT-1-j) : j;
    px[j] = *(const uint4*)(xap + (size_t)tj*128);
  }
  const ushort_t* xpp = xap + (size_t)(dir ? (TT-5) : 4)*128;
  const int xstep = dir ? -128 : 128;
  __syncthreads();

  const floatx4 z4 = {0.f,0.f,0.f,0.f};
  const intx4  zi = {0,0,0,0};
  float cst = 0.f;
  const int t00 = dir ? TT-1 : 0;
  ushort_t* hp = h0seq + ((size_t)(cb*4 + q)*TT + t00)*256 + dir*128 + u;
  const int hstep = dir ? -256 : 256;

  const int ch = m >> 2;

  for (int i = 0; i < TT/4; ++i){
    #pragma unroll
    for (int p = 0; p < 4; ++p){
      const int s = i*4 + p;
      const int cur = s & 1, nxt = cur ^ 1;

      const char* ar = &AbufC[cur][ch][0];
      intx4 AfQ0 = *(const intx4*)(ar + q*16);
      intx4 AfQ1 = *(const intx4*)(ar + 64 + q*16);
      bf16x8 Ax = *(const bf16x8*)&px[p];

      floatx4 ax0 = __builtin_amdgcn_mfma_f32_16x16x32_bf16(Ax, Bfx[0], z4, 0,0,0);
      floatx4 ax1 = __builtin_amdgcn_mfma_f32_16x16x32_bf16(Ax, Bfx[1], z4, 0,0,0);
      floatx4 ax2 = __builtin_amdgcn_mfma_f32_16x16x32_bf16(Ax, Bfx[2], z4, 0,0,0);
      floatx4 ax3 = __builtin_amdgcn_mfma_f32_16x16x32_bf16(Ax, Bfx[3], z4, 0,0,0);

      intx4 aq0 = __builtin_amdgcn_mfma_i32_16x16x64_i8(AfQ0, BfQ[0][0], zi, 0,0,0);
      intx4 aq1 = __builtin_amdgcn_mfma_i32_16x16x64_i8(AfQ0, BfQ[1][0], zi, 0,0,0);
      intx4 aq2 = __builtin_amdgcn_mfma_i32_16x16x64_i8(AfQ0, BfQ[2][0], zi, 0,0,0);
      intx4 aq3 = __builtin_amdgcn_mfma_i32_16x16x64_i8(AfQ0, BfQ[3][0], zi, 0,0,0);
      aq0 = __builtin_amdgcn_mfma_i32_16x16x64_i8(AfQ1, BfQ[0][1], aq0, 0,0,0);
      aq1 = __builtin_amdgcn_mfma_i32_16x16x64_i8(AfQ1, BfQ[1][1], aq1, 0,0,0);
      aq2 = __builtin_amdgcn_mfma_i32_16x16x64_i8(AfQ1, BfQ[2][1], aq2, 0,0,0);
      aq3 = __builtin_amdgcn_mfma_i32_16x16x64_i8(AfQ1, BfQ[3][1], aq3, 0,0,0);

      px[p] = *(const uint4*)xpp;
      xpp += xstep;

      {
        float ig = fsig ((float)aq0[0]*sclc + ax0[0] + bz[0]);
        float fg = fsig ((float)aq1[0]*sclc + ax1[0] + bz[1]);
        float gg = ftanh((float)aq2[0]*sclc + ax2[0] + bz[2]);
        float og = fsig ((float)aq3[0]*sclc + ax3[0] + bz[3]);
        float cc = fg*cst + ig*gg;
        cst = cc;
        float hf = og*ftanh(cc);
        AbufC[nxt][q][u] = (char)(int)rintf(hf * 127.f);
        *hp = f2bf(hf); hp += hstep;
      }
      ldsbar();
    }
  }
}

// ---------------- K2: xz1R[dir][b][t][u(64)][g(4)] = bf16( h0seq[bt][:256] @ Wx1[dir] )
__global__ __launch_bounds__(512) void k_xz1_gemm(const ushort_t* __restrict__ h0seq,
                                                  const ushort_t* __restrict__ WxT,
                                                  ushort_t* __restrict__ xz1)
{
  const int mb  = blockIdx.x;
  const int dir = blockIdx.y;
  const ushort_t* W   = WxT + (size_t)dir*256*256;
  ushort_t*       out = xz1 + (size_t)dir*BB*TT*256;
  const int wave = threadIdx.x >> 6;
  const int lane = threadIdx.x & 63;
  const int mw = wave & 3;
  const int nw = wave >> 2;
  const int m_ = lane & 15;
  const int q_ = lane >> 4;

  floatx4 acc[2][8];
  #pragma unroll
  for (int a=0;a<2;a++)
    #pragma unroll
    for (int n=0;n<8;n++) acc[a][n] = (floatx4)0.f;

  const size_t Abase = ((size_t)mb*128 + mw*32 + m_)*256 + q_*8;
  const size_t Bbase = ((size_t)nw*128 + m_)*256 + q_*8;

  for (int kc = 0; kc < 256; kc += 32){
    bf16x8 afr[2];
    #pragma unroll
    for (int mt=0;mt<2;mt++)
      afr[mt] = *(const bf16x8*)(h0seq + Abase + (size_t)mt*16*256 + kc);
    #pragma unroll
    for (int nt=0;nt<8;nt++){
      bf16x8 bfr = *(const bf16x8*)(W + Bbase + (size_t)nt*16*256 + kc);
      #pragma unroll
      for (int mt=0;mt<2;mt++)
        acc[mt][nt] = __builtin_amdgcn_mfma_f32_16x16x32_bf16(afr[mt], bfr, acc[mt][nt], 0,0,0);
    }
  }
  #pragma unroll
  for (int mt=0;mt<2;mt++)
    #pragma unroll
    for (int r=0;r<4;r++){
      size_t bt = (size_t)mb*128 + mw*32 + mt*16 + q_*4 + r;
      ushort_t* rowp = out + bt*256;
      #pragma unroll
      for (int wvz=0; wvz<4; wvz++){
        uint32_t lo = f2bf(acc[mt][wvz][r]);
        uint32_t hi = f2bf(acc[mt][wvz+4][r]);
        *(uint32_t*)(rowp + (wvz*16+m_)*4 + 2*nw) = lo | (hi << 16);
      }
    }
}

// ---------------- K3: layer-1 scan, v6: BARRIER-FREE, one wave per chain.
// 128 WGs x 64 threads. The wave holds all 64 h units: A = 16 broadcast rows of
// h (int8, K=64), 16 MFMAs (4 gates x 4 unit-tiles) compute all 256 z values;
// C-rows are identical, so every lane holds tile(g,ut)'s z[ut*16+m] -> lane
// (m,q) owns unit u=q*16+m, selecting tile ut=q via 3 cndmask per gate.
// h is re-exchanged through a 64-B LDS scratch with same-wave lgkmcnt ordering
// ONLY — no s_barrier in the 2560-step loop (r6 showed the 4-wave barrier
// skeleton, not MFMA/VALU, was the ~890cyc/step cost).
__global__ __launch_bounds__(64, 1) void k_lstm1m(
  const ushort_t* __restrict__ xz1R,                // [dir][b][t][u][g] bf16
  const char* __restrict__ W1Q,                     // [dir][n=256][k=64] int8
  const float* __restrict__ scl,
  const float* __restrict__ bF, const float* __restrict__ bB,
  float* __restrict__ h1last)                       // [B][128]: fwd 0..63, bwd 64..127
{
  const int dir = blockIdx.x & 1, b = blockIdx.x >> 1;    // b 0..63
  const int lane = threadIdx.x;
  const int m = lane & 15, q = lane >> 4;
  const int u = q*16 + m;                                 // unit 0..63 owned by lane
  const float* bi = dir ? bB : bF;
  const float sclc = scl[2+dir] * (1.f/16129.f);
  const bool qodd = (q & 1), qhi = (q >= 2);

  __shared__ __align__(16) char hbuf[128];                // 64 h bytes (k=unit order)

  // B fragments: tile (g,ut): n = g*64 + ut*16 + m, k-slice q*16..+15
  intx4 BfQ[4][4];
  {
    const char* Bq = W1Q + (size_t)dir*16384;
    #pragma unroll
    for (int g=0; g<4; g++)
      #pragma unroll
      for (int ut=0; ut<4; ut++)
        BfQ[g][ut] = *(const intx4*)(Bq + (size_t)(g*64 + ut*16 + m)*64 + q*16);
  }
  float bz[4];
  #pragma unroll
  for (int g=0; g<4; g++) bz[g] = bi[g*64 + u];

  if (lane < 32) ((uint32_t*)hbuf)[lane] = 0u;            // h0 = 0

  const ushort_t* xzr = xz1R + ((size_t)dir*BB + b)*TT*256 + (size_t)u*4;
  uint2 pz[4];
  #pragma unroll
  for (int j=0; j<4; j++){
    int tj = dir ? (TT-1-j) : j;
    pz[j] = *(const uint2*)(xzr + (size_t)tj*256);
  }
  const ushort_t* xpp = xzr + (size_t)(dir ? (TT-5) : 4)*256;
  const int zstep = dir ? -256 : 256;      // ushorts per step
  ldsfence();                              // h0 zeros visible (same wave)

  const intx4 zi = {0,0,0,0};
  float cst = 0.f, hl = 0.f;

  for (int i = 0; i < TT/4; ++i){
    #pragma unroll
    for (int p = 0; p < 4; ++p){
      // A fragment: lane (m,q) reads k = q*16..+15 (16-lane broadcast per q-group)
      intx4 AfQ = *(const intx4*)(hbuf + q*16);

      // hoisted xz+bias partials + prefetch bump (independent of MFMA)
      float w0 = bz[0] + bf2f((ushort_t)(pz[p].x & 0xffff));
      float w1 = bz[1] + bf2f((ushort_t)(pz[p].x >> 16));
      float w2 = bz[2] + bf2f((ushort_t)(pz[p].y & 0xffff));
      float w3 = bz[3] + bf2f((ushort_t)(pz[p].y >> 16));
      pz[p] = *(const uint2*)xpp;
      xpp += zstep;

      // 16 independent MFMAs: all of z for this chain
      intx4 C[4][4];
      #pragma unroll
      for (int g=0; g<4; g++)
        #pragma unroll
        for (int ut=0; ut<4; ut++)
          C[g][ut] = __builtin_amdgcn_mfma_i32_16x16x64_i8(AfQ, BfQ[g][ut], zi, 0,0,0);

      // per-lane tile select (ut = q): 3 cndmask per gate
      int z0i = qhi ? (qodd ? C[0][3][0] : C[0][2][0]) : (qodd ? C[0][1][0] : C[0][0][0]);
      int z1i = qhi ? (qodd ? C[1][3][0] : C[1][2][0]) : (qodd ? C[1][1][0] : C[1][0][0]);
      int z2i = qhi ? (qodd ? C[2][3][0] : C[2][2][0]) : (qodd ? C[2][1][0] : C[2][0][0]);
      int z3i = qhi ? (qodd ? C[3][3][0] : C[3][2][0]) : (qodd ? C[3][1][0] : C[3][0][0]);

      {
        float ig = fsig((float)z0i*sclc + w0);
        float fg = fsig((float)z1i*sclc + w1);
        float gg = ftanh((float)z2i*sclc + w2);
        float og = fsig((float)z3i*sclc + w3);
        float cc = fg*cst + ig*gg;
        cst = cc;
        hl = og*ftanh(cc);
        hbuf[u] = (char)(int)rintf(hl * 127.f);
      }
      ldsfence();   // same-wave write->read ordering; NO barrier
    }
  }
  h1last[(size_t)b*128 + dir*64 + u] = hl;
}

// ---------------- K4: dense head
__global__ __launch_bounds__(128) void k_head(
  const float* __restrict__ h1last,
  const float* __restrict__ d0W, const float* __restrict__ d0b,
  const float* __restrict__ d1W, const float* __restrict__ d1b,
  const float* __restrict__ oW,  const float* __restrict__ ob,
  float* __restrict__ outp)
{
  const int b = blockIdx.x;
  const int j = threadIdx.x;
  __shared__ float v0[128], v1[128];
  v0[j] = h1last[b*128 + j];
  __syncthreads();
  float acc = d0b[j];
  #pragma unroll
  for (int k=0;k<128;k++) acc += v0[k]*d0W[k*128 + j];
  v1[j] = fmaxf(acc, 0.f);
  __syncthreads();
  if (j < 64){
    float a2 = d1b[j];
    #pragma unroll
    for (int k=0;k<128;k++) a2 += v1[k]*d1W[k*64 + j];
    float p = fmaxf(a2, 0.f) * oW[j];
    #pragma unroll
    for (int off=32; off>0; off>>=1) p += __shfl_down(p, off, 64);
    if (j == 0) outp[b] = 1.f/(1.f + __expf(-(p + ob[0])));
  }
}

extern "C" void kernel_launch(void* const* d_in, const int* in_sizes, int n_in,
                              void* d_out, int out_size, void* d_ws, size_t ws_size,
                              hipStream_t stream)
{
  const float* x     = (const float*)d_in[0];
  const float* l0fWx = (const float*)d_in[1];
  const float* l0fWh = (const float*)d_in[2];
  const float* l0fb  = (const float*)d_in[3];
  const float* l0bWx = (const float*)d_in[4];
  const float* l0bWh = (const float*)d_in[5];
  const float* l0bb  = (const float*)d_in[6];
  const float* l1fWx = (const float*)d_in[7];
  const float* l1fWh = (const float*)d_in[8];
  const float* l1fb  = (const float*)d_in[9];
  const float* l1bWx = (const float*)d_in[10];
  const float* l1bWh = (const float*)d_in[11];
  const float* l1bb  = (const float*)d_in[12];
  const float* d0W = (const float*)d_in[13];
  const float* d0b = (const float*)d_in[14];
  const float* d1W = (const float*)d_in[15];
  const float* d1b = (const float*)d_in[16];
  const float* oW  = (const float*)d_in[17];
  const float* ob  = (const float*)d_in[18];
  float* outp = (float*)d_out;

  char* ws = (char*)d_ws;
  const size_t OFF_XT  = 0;                        // xc: 7,208,960 (slot 7,864,320)
  const size_t OFF_SCL = 7208960ull;               // 16 B (xc slot slack)
  const size_t OFF_H0  = OFF_XT  + 7864320ull;     // 83,886,080
  const size_t OFF_XZ  = OFF_H0  + 83886080ull;    // 167,772,160 (xz1R; xA overlaps head)
  const size_t OFF_XA  = OFF_XZ;                   // xA: 10,485,760 (dead before xz1 written)
  const size_t OFF_WT  = OFF_XZ  + 167772160ull;   // 262,144
  const size_t OFF_B0  = OFF_WT  + 262144ull;      // slot 327,680: W0Q 131,072 + B0X 131,072
  const size_t OFF_B0X = OFF_B0  + 131072ull;
  const size_t OFF_B1  = OFF_B0  + 327680ull;      // slot 65,536: W1Q 32,768
  const size_t OFF_H1  = OFF_B1  + 65536ull;       // 32,768

  ushort_t* xc  = (ushort_t*)(ws + OFF_XT);
  float*    sclp= (float*)(ws + OFF_SCL);
  ushort_t* h0  = (ushort_t*)(ws + OFF_H0);
  ushort_t* xz1 = (ushort_t*)(ws + OFF_XZ);
  ushort_t* xA  = (ushort_t*)(ws + OFF_XA);
  ushort_t* WT  = (ushort_t*)(ws + OFF_WT);
  char*     W0Q = (char*)(ws + OFF_B0);
  ushort_t* B0X = (ushort_t*)(ws + OFF_B0X);
  char*     W1Q = (char*)(ws + OFF_B1);
  float*    h1l = (float*)(ws + OFF_H1);

  hipLaunchKernelGGL(k_convert_x,   dim3(3520), dim3(256), 0, stream, x, xc);
  hipLaunchKernelGGL(k_prep_xa,     dim3(2560), dim3(256), 0, stream, xc, xA);
  hipLaunchKernelGGL(k_wmax,        dim3(4),    dim3(256), 0, stream, l0fWh, l0bWh, l1fWh, l1bWh, sclp);
  hipLaunchKernelGGL(k_prep_l0,     dim3(640),  dim3(256), 0, stream, l0fWx, l0fWh, l0bWx, l0bWh, sclp, W0Q, B0X);
  hipLaunchKernelGGL(k_prep_l1,     dim3(128),  dim3(256), 0, stream, l1fWh, l1bWh, sclp, W1Q);
  hipLaunchKernelGGL(k_prep_wxT,    dim3(512),  dim3(256), 0, stream, l1fWx, l1bWx, WT);
  hipLaunchKernelGGL(k_lstm0m,      dim3(32),   dim3(512), 0, stream, xA, W0Q, B0X, sclp, l0fb, l0bb, h0);
  hipLaunchKernelGGL(k_xz1_gemm,    dim3(1280,2), dim3(512), 0, stream, h0, WT, xz1);
  hipLaunchKernelGGL(k_lstm1m,      dim3(128),  dim3(64), 0, stream, xz1, W1Q, sclp, l1fb, l1bb, h1l);
  hipLaunchKernelGGL(k_head,        dim3(64),   dim3(128), 0, stream,
                     h1l, d0W, d0b, d1W, d1b, oW, ob, outp);
}

// Round 8
// 2131.298 us; speedup vs baseline: 1.2842x; 1.2842x over previous
//
#include <hip/hip_runtime.h>
#include <stdint.h>

#define TT 2560
#define BB 64
#define CC 22

typedef unsigned short ushort_t;
typedef __attribute__((ext_vector_type(4))) float floatx4;
typedef __attribute__((ext_vector_type(8))) short bf16x8;
typedef __attribute__((ext_vector_type(4))) int intx4;

__device__ __forceinline__ float bf2f(ushort_t u){
  union { uint32_t i; float f; } v; v.i = ((uint32_t)u) << 16; return v.f;
}
__device__ __forceinline__ ushort_t f2bf(float f){
  union { float f; uint32_t i; } v; v.f = f;
  uint32_t r = v.i + 0x7FFFu + ((v.i >> 16) & 1u);
  return (ushort_t)(r >> 16);
}
__device__ __forceinline__ float fsig(float x){ return 1.f/(1.f + __expf(-x)); }
__device__ __forceinline__ float ftanh(float x){ return 2.f/(1.f + __expf(-2.f*x)) - 1.f; }

// LDS-only barrier: does NOT drain vmcnt; global stores/prefetch loads stay in
// flight across the 2560-step serial loop.
__device__ __forceinline__ void ldsbar(){
  asm volatile("s_waitcnt lgkmcnt(0)\n\ts_barrier" ::: "memory");
}

// ---------------- K0a: cast x [B][C][T] fp32 -> xc [B][C][T] bf16 (time-contiguous)
__global__ __launch_bounds__(256) void k_convert_x(const float* __restrict__ x, ushort_t* __restrict__ xc){
  int i4 = blockIdx.x*256 + threadIdx.x;
  if (i4 >= BB*CC*TT/4) return;
  const float4 v = ((const float4*)x)[i4];
  uint2 o;
  o.x = (uint32_t)f2bf(v.x) | ((uint32_t)f2bf(v.y) << 16);
  o.y = (uint32_t)f2bf(v.z) | ((uint32_t)f2bf(v.w) << 16);
  ((uint2*)xc)[i4] = o;
}

// ---------------- K0a2: pack x into q-only A-fragment order (v7).
// xA[b][t][q][8]: lane (m,q) holds x channels q*8..q*8+7 (bf16, 0-padded >=22);
// value independent of m (A rows are replicas).
__global__ __launch_bounds__(256) void k_prep_xa(const ushort_t* __restrict__ xc, ushort_t* __restrict__ xA){
  int idx = blockIdx.x*256 + threadIdx.x;          // ((b*TT + t)*4 + q)
  if (idx >= BB*TT*4) return;
  int q = idx & 3;
  int rest = idx >> 2;
  int t = rest % TT, b = rest / TT;
  ushort_t v[8];
  #pragma unroll
  for (int j=0;j<8;j++){
    int c = q*8 + j;
    v[j] = (c < CC) ? xc[((size_t)b*CC + c)*TT + t] : (ushort_t)0;
  }
  *(uint4*)(xA + (size_t)idx*8) = *(const uint4*)v;
}

// ---------------- K0w: per-tensor absmax of the 4 recurrent weight matrices.
__global__ __launch_bounds__(256) void k_wmax(const float* __restrict__ w0f, const float* __restrict__ w0b,
                                              const float* __restrict__ w1f, const float* __restrict__ w1b,
                                              float* __restrict__ scl){
  const int b = blockIdx.x;
  const float* W = (b==0) ? w0f : (b==1) ? w0b : (b==2) ? w1f : w1b;
  const int n = (b < 2) ? 128*512 : 64*256;
  float mx = 0.f;
  for (int i = threadIdx.x; i < n; i += 256) mx = fmaxf(mx, fabsf(W[i]));
  __shared__ float red[256];
  red[threadIdx.x] = mx;
  __syncthreads();
  for (int s = 128; s > 0; s >>= 1){
    if (threadIdx.x < s) red[threadIdx.x] = fmaxf(red[threadIdx.x], red[threadIdx.x+s]);
    __syncthreads();
  }
  if (threadIdx.x == 0) scl[b] = fmaxf(red[0], 1e-8f);
}

// ---------------- K0b: layer-0 weights, v7 PERMUTED n-tile layout.
// n = g*128 + u (g=gate, u=unit); u = wv*16 + qq*4 + r.
// Dest row = (qq*8 + wv)*16 + (r*4 + g): the MFMA for lane-quarter qq of wave wv
// delivers z[n] at column m = r*4+g.
__global__ __launch_bounds__(256) void k_prep_l0(const float* __restrict__ WxF, const float* __restrict__ WhF,
                                                 const float* __restrict__ WxB, const float* __restrict__ WhB,
                                                 const float* __restrict__ scl,
                                                 char* __restrict__ W0Q, ushort_t* __restrict__ B0X){
  int idx = blockIdx.x*256 + threadIdx.x;
  if (idx >= 2*512*160) return;
  int dir = idx / 81920; int r0 = idx % 81920; int n = r0 / 160; int k = r0 % 160;
  int g = n >> 7, u = n & 127;
  int wv = u >> 4, qq = (u >> 2) & 3, r = u & 3;
  int row = (qq*8 + wv)*16 + (r*4 + g);
  if (k < 128){
    const float* Wh = dir ? WhB : WhF;
    float sw = scl[dir];
    W0Q[(size_t)dir*65536 + row*128 + k] = (char)(int)rintf(Wh[k*512 + n] * (127.f/sw));
  } else {
    const float* Wx = dir ? WxB : WxF;
    int kx = k - 128;
    float v = (kx < CC) ? Wx[kx*512 + n] : 0.f;
    B0X[(size_t)dir*16384 + row*32 + kx] = f2bf(v);
  }
}

// ---------------- K0c: W1Q[dir][n=256][k=64] int8 = round(Wh1[k][n] * 127/sw)
__global__ __launch_bounds__(256) void k_prep_l1(const float* __restrict__ WhF, const float* __restrict__ WhB,
                                                 const float* __restrict__ scl,
                                                 char* __restrict__ W1Q){
  int idx = blockIdx.x*256 + threadIdx.x;
  if (idx >= 2*256*64) return;
  int dir = idx >> 14; int r = idx & 16383; int n = r >> 6; int k = r & 63;
  const float* Wh = dir ? WhB : WhF;
  float sw = scl[2+dir];
  W1Q[(size_t)dir*16384 + n*64 + k] = (char)(int)rintf(Wh[k*256 + n] * (127.f/sw));
}

// ---------------- K0d: WT[dir][n=256][k=256] = Wx1[k][n]  (for xz1 gemm)
__global__ __launch_bounds__(256) void k_prep_wxT(const float* __restrict__ Wf, const float* __restrict__ Wb,
                                                  ushort_t* __restrict__ WT){
  int idx = blockIdx.x*256 + threadIdx.x;
  int dir = idx >> 16; int r = idx & 65535; int n = r >> 8; int k = r & 255;
  const float* W = dir ? Wb : Wf;
  WT[idx] = f2bf(W[k*256 + n]);
}

// ---------------- K1: layer-0 scan v7: ONE chain per WG, 128 WGs, 8 waves.
// r6 PMC showed VALUBusy ~73%/active-CU vs MFMA ~30%: the 4 transcendental
// chains per lane were the limiter. Now each lane owns ONE z value
// (gate g=m&3, unit u=wv*16+q*4+(m>>2)); per-lane gate VALU drops 4x while
// per-SIMD MFMA time is invariant (A-row replication waste exactly cancels the
// 4x CU spread). i,f,g^,o of a unit sit in 4 adjacent lanes -> combine via
// 3 ds_swizzle (xor1/2/3, in-half) into the g=0 lane which owns c-state.
__global__ __launch_bounds__(512, 1) void k_lstm0m(
  const ushort_t* __restrict__ xA, const char* __restrict__ W0Q,
  const ushort_t* __restrict__ B0X, const float* __restrict__ scl,
  const float* __restrict__ bF, const float* __restrict__ bB,
  ushort_t* __restrict__ h0seq)                     // [B][T][256]: fwd 0..127, bwd 128..255
{
  const int dir = blockIdx.x & 1, b = blockIdx.x >> 1;    // b 0..63
  const int tid = threadIdx.x;
  const int wv = tid >> 6, lane = tid & 63, m = lane & 15, q = lane >> 4;
  const int g  = m & 3;                                   // gate of this lane
  const int u  = wv*16 + q*4 + (m >> 2);                  // unit of this lane
  const float* bi = dir ? bB : bF;
  const float sclc = scl[dir] * (1.f/16129.f);            // sw/(127*127)
  // activation constants: gate 2 is tanh = 2*sigmoid(2x)-1 (exact: x2 is lossless)
  const float em = (g==2) ? -2.f : -1.f;
  const float ym = (g==2) ?  2.f :  1.f;
  const float ya = (g==2) ? -1.f :  0.f;
  const float bzl = bi[g*128 + u];

  __shared__ __align__(16) char AbufC[2][128];            // h int8, double-buffered

  // B fragments: tile qt (lane-quarter) -> rows (qt*8+wv)*16 + m
  bf16x8 Bfx[4];
  intx4  BfQ[4][2];
  {
    const ushort_t* Bx = B0X + (size_t)dir*16384;
    const char*     Bq = W0Q + (size_t)dir*65536;
    #pragma unroll
    for (int qt=0; qt<4; qt++){
      int nrow = (qt*8 + wv)*16 + m;
      Bfx[qt] = *(const bf16x8*)(Bx + (size_t)nrow*32 + q*8);
      #pragma unroll
      for (int kt=0; kt<2; kt++)
        BfQ[qt][kt] = *(const intx4*)(Bq + (size_t)nrow*128 + kt*64 + q*16);
    }
  }

  if (tid < 64) ((uint32_t*)AbufC)[tid] = 0u;             // zero both buffers

  // x fragment stream: value depends only on q (16-lane broadcast loads)
  const ushort_t* xap = xA + ((size_t)b*TT*4 + q)*8;
  uint4 px[4];
  #pragma unroll
  for (int j=0; j<4; j++){
    int tj = dir ? (TT-1-j) : j;
    px[j] = *(const uint4*)(xap + (size_t)tj*32);
  }
  const ushort_t* xpp = xap + (size_t)(dir ? (TT-5) : 4)*32;
  const int xstep = dir ? -32 : 32;   // ushorts per step
  __syncthreads();

  const floatx4 z4 = {0.f,0.f,0.f,0.f};
  const intx4  zi = {0,0,0,0};
  float cst = 0.f;
  const int t00 = dir ? TT-1 : 0;
  ushort_t* hp = h0seq + ((size_t)b*TT + t00)*256 + dir*128 + u;
  const int hstep = dir ? -256 : 256;

  for (int i = 0; i < TT/4; ++i){
    #pragma unroll
    for (int p = 0; p < 4; ++p){
      const int s = i*4 + p;
      const int cur = s & 1, nxt = cur ^ 1;

      const char* ar = &AbufC[cur][0];
      intx4 AfQ0 = *(const intx4*)(ar + q*16);
      intx4 AfQ1 = *(const intx4*)(ar + 64 + q*16);
      bf16x8 Ax = *(const bf16x8*)&px[p];

      // 4 independent tile-chains (x bf16 first: register operands cover ds_read)
      floatx4 ax0 = __builtin_amdgcn_mfma_f32_16x16x32_bf16(Ax, Bfx[0], z4, 0,0,0);
      floatx4 ax1 = __builtin_amdgcn_mfma_f32_16x16x32_bf16(Ax, Bfx[1], z4, 0,0,0);
      floatx4 ax2 = __builtin_amdgcn_mfma_f32_16x16x32_bf16(Ax, Bfx[2], z4, 0,0,0);
      floatx4 ax3 = __builtin_amdgcn_mfma_f32_16x16x32_bf16(Ax, Bfx[3], z4, 0,0,0);

      intx4 aq0 = __builtin_amdgcn_mfma_i32_16x16x64_i8(AfQ0, BfQ[0][0], zi, 0,0,0);
      intx4 aq1 = __builtin_amdgcn_mfma_i32_16x16x64_i8(AfQ0, BfQ[1][0], zi, 0,0,0);
      intx4 aq2 = __builtin_amdgcn_mfma_i32_16x16x64_i8(AfQ0, BfQ[2][0], zi, 0,0,0);
      intx4 aq3 = __builtin_amdgcn_mfma_i32_16x16x64_i8(AfQ0, BfQ[3][0], zi, 0,0,0);
      aq0 = __builtin_amdgcn_mfma_i32_16x16x64_i8(AfQ1, BfQ[0][1], aq0, 0,0,0);
      aq1 = __builtin_amdgcn_mfma_i32_16x16x64_i8(AfQ1, BfQ[1][1], aq1, 0,0,0);
      aq2 = __builtin_amdgcn_mfma_i32_16x16x64_i8(AfQ1, BfQ[2][1], aq2, 0,0,0);
      aq3 = __builtin_amdgcn_mfma_i32_16x16x64_i8(AfQ1, BfQ[3][1], aq3, 0,0,0);

      // px reload for step s+4
      px[p] = *(const uint4*)xpp;
      xpp += xstep;

      // select this lane's tile (qt = q): 3 cndmask per operand
      float axs = (q < 2) ? ((q == 0) ? ax0[0] : ax1[0])
                          : ((q == 2) ? ax2[0] : ax3[0]);
      int   aqs = (q < 2) ? ((q == 0) ? aq0[0] : aq1[0])
                          : ((q == 2) ? aq2[0] : aq3[0]);

      {
        float z = (float)aqs*sclc + axs + bzl;
        float e = __expf(z * em);
        float y = 1.f/(1.f + e);
        float act = ym*y + ya;               // sigmoid or tanh (exact)

        int ai = __float_as_int(act);
        float sf = __int_as_float(__builtin_amdgcn_ds_swizzle(ai, 0x041F)); // ^1 -> f
        float sg = __int_as_float(__builtin_amdgcn_ds_swizzle(ai, 0x081F)); // ^2 -> g^
        float so = __int_as_float(__builtin_amdgcn_ds_swizzle(ai, 0x0C1F)); // ^3 -> o

        float cc = sf*cst + act*sg;          // f*c + i*g^   (valid in g==0 lanes)
        cst = cc;
        float hl = so*ftanh(cc);             // o*tanh(c)
        if (g == 0){
          AbufC[nxt][u] = (char)(int)rintf(hl * 127.f);
          *hp = f2bf(hl);                    // fire-and-forget bf16 h
        }
        hp += hstep;
      }
      ldsbar();
    }
  }
}

// ---------------- K2: xz1R[dir][b][t][u(64)][g(4)] = bf16( h0seq[bt][:256] @ Wx1[dir] )
__global__ __launch_bounds__(512) void k_xz1_gemm(const ushort_t* __restrict__ h0seq,
                                                  const ushort_t* __restrict__ WxT,
                                                  ushort_t* __restrict__ xz1)
{
  const int mb  = blockIdx.x;
  const int dir = blockIdx.y;
  const ushort_t* W   = WxT + (size_t)dir*256*256;
  ushort_t*       out = xz1 + (size_t)dir*BB*TT*256;
  const int wave = threadIdx.x >> 6;
  const int lane = threadIdx.x & 63;
  const int mw = wave & 3;
  const int nw = wave >> 2;
  const int m_ = lane & 15;
  const int q_ = lane >> 4;

  floatx4 acc[2][8];
  #pragma unroll
  for (int a=0;a<2;a++)
    #pragma unroll
    for (int n=0;n<8;n++) acc[a][n] = (floatx4)0.f;

  const size_t Abase = ((size_t)mb*128 + mw*32 + m_)*256 + q_*8;
  const size_t Bbase = ((size_t)nw*128 + m_)*256 + q_*8;

  for (int kc = 0; kc < 256; kc += 32){
    bf16x8 afr[2];
    #pragma unroll
    for (int mt=0;mt<2;mt++)
      afr[mt] = *(const bf16x8*)(h0seq + Abase + (size_t)mt*16*256 + kc);
    #pragma unroll
    for (int nt=0;nt<8;nt++){
      bf16x8 bfr = *(const bf16x8*)(W + Bbase + (size_t)nt*16*256 + kc);
      #pragma unroll
      for (int mt=0;mt<2;mt++)
        acc[mt][nt] = __builtin_amdgcn_mfma_f32_16x16x32_bf16(afr[mt], bfr, acc[mt][nt], 0,0,0);
    }
  }
  #pragma unroll
  for (int mt=0;mt<2;mt++)
    #pragma unroll
    for (int r=0;r<4;r++){
      size_t bt = (size_t)mb*128 + mw*32 + mt*16 + q_*4 + r;
      ushort_t* rowp = out + bt*256;
      #pragma unroll
      for (int wvz=0; wvz<4; wvz++){
        uint32_t lo = f2bf(acc[mt][wvz][r]);
        uint32_t hi = f2bf(acc[mt][wvz+4][r]);
        *(uint32_t*)(rowp + (wvz*16+m_)*4 + 2*nw) = lo | (hi << 16);
      }
    }
}

// ---------------- K3: layer-1 scan, int8 recurrence (r6-proven v5, reverted).
__global__ __launch_bounds__(256, 1) void k_lstm1m(
  const ushort_t* __restrict__ xz1R,                // [dir][b][t][u][g] bf16
  const char* __restrict__ W1Q,                     // [dir][n=256][k=64] int8
  const float* __restrict__ scl,
  const float* __restrict__ bF, const float* __restrict__ bB,
  float* __restrict__ h1last)                       // [B][128]: fwd 0..63, bwd 64..127
{
  const int dir = blockIdx.x & 1, cb = blockIdx.x >> 1;   // cb 0..15
  const int tid = threadIdx.x;
  const int wv = tid >> 6, lane = tid & 63, m = lane & 15, q = lane >> 4;
  const int u = wv*16 + m;                                // unit 0..63
  const float* bi = dir ? bB : bF;
  const float sclc = scl[2+dir] * (1.f/16129.f);

  __shared__ __align__(16) char HbufC[2][4][80];

  intx4 BfQ[4];                           // gate g -> n-tile g*4+wv, whole K=64
  {
    const char* Bq = W1Q + (size_t)dir*16384;
    #pragma unroll
    for (int g=0; g<4; g++){
      int nrow = (g*4 + wv)*16 + m;
      BfQ[g] = *(const intx4*)(Bq + (size_t)nrow*64 + q*16);
    }
  }
  float bz[4];
  #pragma unroll
  for (int g=0; g<4; g++) bz[g] = bi[g*64 + u];

  if (tid < (int)(sizeof(HbufC)/4)) ((uint32_t*)HbufC)[tid] = 0u;

  const ushort_t* xzr = xz1R + ((size_t)dir*BB + (size_t)(cb*4+q))*TT*256 + (size_t)u*4;
  uint2 pz[4];
  #pragma unroll
  for (int j=0; j<4; j++){
    int tj = dir ? (TT-1-j) : j;
    pz[j] = *(const uint2*)(xzr + (size_t)tj*256);
  }
  const ushort_t* xpp = xzr + (size_t)(dir ? (TT-5) : 4)*256;
  const int zstep = dir ? -256 : 256;      // ushorts per step
  __syncthreads();

  const intx4 zi = {0,0,0,0};
  float cst = 0.f, hl = 0.f;
  const int ch = m >> 2;                   // chain row

  for (int i = 0; i < TT/4; ++i){
    #pragma unroll
    for (int p = 0; p < 4; ++p){
      const int s = i*4 + p;
      const int cur = s & 1, nxt = cur ^ 1;

      intx4 AfQ = *(const intx4*)(&HbufC[cur][ch][0] + q*16);

      // hoisted xz+bias partials under the ds_read shadow
      float w0 = bz[0] + bf2f((ushort_t)(pz[p].x & 0xffff));
      float w1 = bz[1] + bf2f((ushort_t)(pz[p].x >> 16));
      float w2 = bz[2] + bf2f((ushort_t)(pz[p].y & 0xffff));
      float w3 = bz[3] + bf2f((ushort_t)(pz[p].y >> 16));
      pz[p] = *(const uint2*)xpp;
      xpp += zstep;

      intx4 a0 = __builtin_amdgcn_mfma_i32_16x16x64_i8(AfQ, BfQ[0], zi, 0,0,0);
      intx4 a1 = __builtin_amdgcn_mfma_i32_16x16x64_i8(AfQ, BfQ[1], zi, 0,0,0);
      intx4 a2 = __builtin_amdgcn_mfma_i32_16x16x64_i8(AfQ, BfQ[2], zi, 0,0,0);
      intx4 a3 = __builtin_amdgcn_mfma_i32_16x16x64_i8(AfQ, BfQ[3], zi, 0,0,0);

      {
        float ig = fsig((float)a0[0]*sclc + w0);
        float fg = fsig((float)a1[0]*sclc + w1);
        float gg = ftanh((float)a2[0]*sclc + w2);
        float og = fsig((float)a3[0]*sclc + w3);
        float cc = fg*cst + ig*gg;
        cst = cc;
        hl = og*ftanh(cc);
        HbufC[nxt][q][u] = (char)(int)rintf(hl * 127.f);
      }
      ldsbar();
    }
  }
  h1last[(size_t)(cb*4 + q)*128 + dir*64 + u] = hl;
}

// ---------------- K4: dense head
__global__ __launch_bounds__(128) void k_head(
  const float* __restrict__ h1last,
  const float* __restrict__ d0W, const float* __restrict__ d0b,
  const float* __restrict__ d1W, const float* __restrict__ d1b,
  const float* __restrict__ oW,  const float* __restrict__ ob,
  float* __restrict__ outp)
{
  const int b = blockIdx.x;
  const int j = threadIdx.x;
  __shared__ float v0[128], v1[128];
  v0[j] = h1last[b*128 + j];
  __syncthreads();
  float acc = d0b[j];
  #pragma unroll
  for (int k=0;k<128;k++) acc += v0[k]*d0W[k*128 + j];
  v1[j] = fmaxf(acc, 0.f);
  __syncthreads();
  if (j < 64){
    float a2 = d1b[j];
    #pragma unroll
    for (int k=0;k<128;k++) a2 += v1[k]*d1W[k*64 + j];
    float p = fmaxf(a2, 0.f) * oW[j];
    #pragma unroll
    for (int off=32; off>0; off>>=1) p += __shfl_down(p, off, 64);
    if (j == 0) outp[b] = 1.f/(1.f + __expf(-(p + ob[0])));
  }
}

extern "C" void kernel_launch(void* const* d_in, const int* in_sizes, int n_in,
                              void* d_out, int out_size, void* d_ws, size_t ws_size,
                              hipStream_t stream)
{
  const float* x     = (const float*)d_in[0];
  const float* l0fWx = (const float*)d_in[1];
  const float* l0fWh = (const float*)d_in[2];
  const float* l0fb  = (const float*)d_in[3];
  const float* l0bWx = (const float*)d_in[4];
  const float* l0bWh = (const float*)d_in[5];
  const float* l0bb  = (const float*)d_in[6];
  const float* l1fWx = (const float*)d_in[7];
  const float* l1fWh = (const float*)d_in[8];
  const float* l1fb  = (const float*)d_in[9];
  const float* l1bWx = (const float*)d_in[10];
  const float* l1bWh = (const float*)d_in[11];
  const float* l1bb  = (const float*)d_in[12];
  const float* d0W = (const float*)d_in[13];
  const float* d0b = (const float*)d_in[14];
  const float* d1W = (const float*)d_in[15];
  const float* d1b = (const float*)d_in[16];
  const float* oW  = (const float*)d_in[17];
  const float* ob  = (const float*)d_in[18];
  float* outp = (float*)d_out;

  char* ws = (char*)d_ws;
  const size_t OFF_XT  = 0;                        // xc: 7,208,960 (slot 7,864,320)
  const size_t OFF_SCL = 7208960ull;               // 16 B (xc slot slack)
  const size_t OFF_H0  = OFF_XT  + 7864320ull;     // 83,886,080
  const size_t OFF_XZ  = OFF_H0  + 83886080ull;    // 167,772,160 (xz1R; xA overlaps head)
  const size_t OFF_XA  = OFF_XZ;                   // xA: 10,485,760 (dead before xz1 written)
  const size_t OFF_WT  = OFF_XZ  + 167772160ull;   // 262,144
  const size_t OFF_B0  = OFF_WT  + 262144ull;      // slot 327,680: W0Q 131,072 + B0X 65,536
  const size_t OFF_B0X = OFF_B0  + 131072ull;
  const size_t OFF_B1  = OFF_B0  + 327680ull;      // slot 65,536: W1Q 32,768
  const size_t OFF_H1  = OFF_B1  + 65536ull;       // 32,768

  ushort_t* xc  = (ushort_t*)(ws + OFF_XT);
  float*    sclp= (float*)(ws + OFF_SCL);
  ushort_t* h0  = (ushort_t*)(ws + OFF_H0);
  ushort_t* xz1 = (ushort_t*)(ws + OFF_XZ);
  ushort_t* xA  = (ushort_t*)(ws + OFF_XA);
  ushort_t* WT  = (ushort_t*)(ws + OFF_WT);
  char*     W0Q = (char*)(ws + OFF_B0);
  ushort_t* B0X = (ushort_t*)(ws + OFF_B0X);
  char*     W1Q = (char*)(ws + OFF_B1);
  float*    h1l = (float*)(ws + OFF_H1);

  hipLaunchKernelGGL(k_convert_x,   dim3(3520), dim3(256), 0, stream, x, xc);
  hipLaunchKernelGGL(k_prep_xa,     dim3(2560), dim3(256), 0, stream, xc, xA);
  hipLaunchKernelGGL(k_wmax,        dim3(4),    dim3(256), 0, stream, l0fWh, l0bWh, l1fWh, l1bWh, sclp);
  hipLaunchKernelGGL(k_prep_l0,     dim3(640),  dim3(256), 0, stream, l0fWx, l0fWh, l0bWx, l0bWh, sclp, W0Q, B0X);
  hipLaunchKernelGGL(k_prep_l1,     dim3(128),  dim3(256), 0, stream, l1fWh, l1bWh, sclp, W1Q);
  hipLaunchKernelGGL(k_prep_wxT,    dim3(512),  dim3(256), 0, stream, l1fWx, l1bWx, WT);
  hipLaunchKernelGGL(k_lstm0m,      dim3(128),  dim3(512), 0, stream, xA, W0Q, B0X, sclp, l0fb, l0bb, h0);
  hipLaunchKernelGGL(k_xz1_gemm,    dim3(1280,2), dim3(512), 0, stream, h0, WT, xz1);
  hipLaunchKernelGGL(k_lstm1m,      dim3(32),   dim3(256), 0, stream, xz1, W1Q, sclp, l1fb, l1bb, h1l);
  hipLaunchKernelGGL(k_head,        dim3(64),   dim3(128), 0, stream,
                     h1l, d0W, d0b, d1W, d1b, oW, ob, outp);
}

// Round 9
// 2105.706 us; speedup vs baseline: 1.2998x; 1.0122x over previous
//
#include <hip/hip_runtime.h>
#include <stdint.h>

#define TT 2560
#define BB 64
#define CC 22

typedef unsigned short ushort_t;
typedef __attribute__((ext_vector_type(4))) float floatx4;
typedef __attribute__((ext_vector_type(8))) short bf16x8;
typedef __attribute__((ext_vector_type(4))) int intx4;

__device__ __forceinline__ float bf2f(ushort_t u){
  union { uint32_t i; float f; } v; v.i = ((uint32_t)u) << 16; return v.f;
}
__device__ __forceinline__ ushort_t f2bf(float f){
  union { float f; uint32_t i; } v; v.f = f;
  uint32_t r = v.i + 0x7FFFu + ((v.i >> 16) & 1u);
  return (ushort_t)(r >> 16);
}
__device__ __forceinline__ float fsig(float x){ return 1.f/(1.f + __expf(-x)); }
__device__ __forceinline__ float ftanh(float x){ return 2.f/(1.f + __expf(-2.f*x)) - 1.f; }

// LDS-only barrier: does NOT drain vmcnt; global stores/prefetch loads stay in
// flight across the 2560-step serial loop.
__device__ __forceinline__ void ldsbar(){
  asm volatile("s_waitcnt lgkmcnt(0)\n\ts_barrier" ::: "memory");
}

// ---------------- K0a: cast x [B][C][T] fp32 -> xc [B][C][T] bf16 (time-contiguous)
__global__ __launch_bounds__(256) void k_convert_x(const float* __restrict__ x, ushort_t* __restrict__ xc){
  int i4 = blockIdx.x*256 + threadIdx.x;
  if (i4 >= BB*CC*TT/4) return;
  const float4 v = ((const float4*)x)[i4];
  uint2 o;
  o.x = (uint32_t)f2bf(v.x) | ((uint32_t)f2bf(v.y) << 16);
  o.y = (uint32_t)f2bf(v.z) | ((uint32_t)f2bf(v.w) << 16);
  ((uint2*)xc)[i4] = o;
}

// ---------------- K0a2: pack x into q-only A-fragment order (v7).
// xA[b][t][q][8]: lane (m,q) holds x channels q*8..q*8+7 (bf16, 0-padded >=22);
// value independent of m (A rows are replicas).
__global__ __launch_bounds__(256) void k_prep_xa(const ushort_t* __restrict__ xc, ushort_t* __restrict__ xA){
  int idx = blockIdx.x*256 + threadIdx.x;          // ((b*TT + t)*4 + q)
  if (idx >= BB*TT*4) return;
  int q = idx & 3;
  int rest = idx >> 2;
  int t = rest % TT, b = rest / TT;
  ushort_t v[8];
  #pragma unroll
  for (int j=0;j<8;j++){
    int c = q*8 + j;
    v[j] = (c < CC) ? xc[((size_t)b*CC + c)*TT + t] : (ushort_t)0;
  }
  *(uint4*)(xA + (size_t)idx*8) = *(const uint4*)v;
}

// ---------------- K0w: per-tensor absmax of the 4 recurrent weight matrices.
__global__ __launch_bounds__(256) void k_wmax(const float* __restrict__ w0f, const float* __restrict__ w0b,
                                              const float* __restrict__ w1f, const float* __restrict__ w1b,
                                              float* __restrict__ scl){
  const int b = blockIdx.x;
  const float* W = (b==0) ? w0f : (b==1) ? w0b : (b==2) ? w1f : w1b;
  const int n = (b < 2) ? 128*512 : 64*256;
  float mx = 0.f;
  for (int i = threadIdx.x; i < n; i += 256) mx = fmaxf(mx, fabsf(W[i]));
  __shared__ float red[256];
  red[threadIdx.x] = mx;
  __syncthreads();
  for (int s = 128; s > 0; s >>= 1){
    if (threadIdx.x < s) red[threadIdx.x] = fmaxf(red[threadIdx.x], red[threadIdx.x+s]);
    __syncthreads();
  }
  if (threadIdx.x == 0) scl[b] = fmaxf(red[0], 1e-8f);
}

// ---------------- K0b: layer-0 weights, v7 PERMUTED n-tile layout.
// n = g*128 + u (g=gate, u=unit); u = wv*16 + qq*4 + r.
// Dest row = (qq*8 + wv)*16 + (r*4 + g): the MFMA for lane-quarter qq of wave wv
// delivers z[n] at column m = r*4+g.
__global__ __launch_bounds__(256) void k_prep_l0(const float* __restrict__ WxF, const float* __restrict__ WhF,
                                                 const float* __restrict__ WxB, const float* __restrict__ WhB,
                                                 const float* __restrict__ scl,
                                                 char* __restrict__ W0Q, ushort_t* __restrict__ B0X){
  int idx = blockIdx.x*256 + threadIdx.x;
  if (idx >= 2*512*160) return;
  int dir = idx / 81920; int r0 = idx % 81920; int n = r0 / 160; int k = r0 % 160;
  int g = n >> 7, u = n & 127;
  int wv = u >> 4, qq = (u >> 2) & 3, r = u & 3;
  int row = (qq*8 + wv)*16 + (r*4 + g);
  if (k < 128){
    const float* Wh = dir ? WhB : WhF;
    float sw = scl[dir];
    W0Q[(size_t)dir*65536 + row*128 + k] = (char)(int)rintf(Wh[k*512 + n] * (127.f/sw));
  } else {
    const float* Wx = dir ? WxB : WxF;
    int kx = k - 128;
    float v = (kx < CC) ? Wx[kx*512 + n] : 0.f;
    B0X[(size_t)dir*16384 + row*32 + kx] = f2bf(v);
  }
}

// ---------------- K0c: layer-1 weights, v8 PERMUTED n-tile layout (same scheme).
// n = g*64 + u; u = wv*16 + qq*4 + r (wv 0..3). Dest row = (qq*4 + wv)*16 + (r*4 + g).
__global__ __launch_bounds__(256) void k_prep_l1(const float* __restrict__ WhF, const float* __restrict__ WhB,
                                                 const float* __restrict__ scl,
                                                 char* __restrict__ W1Q){
  int idx = blockIdx.x*256 + threadIdx.x;
  if (idx >= 2*256*64) return;
  int dir = idx >> 14; int r0 = idx & 16383; int n = r0 >> 6; int k = r0 & 63;
  int g = n >> 6, u = n & 63;
  int wv = u >> 4, qq = (u >> 2) & 3, r = u & 3;
  int row = (qq*4 + wv)*16 + (r*4 + g);
  const float* Wh = dir ? WhB : WhF;
  float sw = scl[2+dir];
  W1Q[(size_t)dir*16384 + row*64 + k] = (char)(int)rintf(Wh[k*256 + n] * (127.f/sw));
}

// ---------------- K0d: WT[dir][n=256][k=256] = Wx1[k][n]  (for xz1 gemm)
__global__ __launch_bounds__(256) void k_prep_wxT(const float* __restrict__ Wf, const float* __restrict__ Wb,
                                                  ushort_t* __restrict__ WT){
  int idx = blockIdx.x*256 + threadIdx.x;
  int dir = idx >> 16; int r = idx & 65535; int n = r >> 8; int k = r & 255;
  const float* W = dir ? Wb : Wf;
  WT[idx] = f2bf(W[k*256 + n]);
}

// ---------------- K1: layer-0 scan v7 (r8-proven, unchanged): one chain/WG,
// 128 WGs, 8 waves; each lane owns one z value; swizzle gate-combine.
__global__ __launch_bounds__(512, 1) void k_lstm0m(
  const ushort_t* __restrict__ xA, const char* __restrict__ W0Q,
  const ushort_t* __restrict__ B0X, const float* __restrict__ scl,
  const float* __restrict__ bF, const float* __restrict__ bB,
  ushort_t* __restrict__ h0seq)                     // [B][T][256]: fwd 0..127, bwd 128..255
{
  const int dir = blockIdx.x & 1, b = blockIdx.x >> 1;    // b 0..63
  const int tid = threadIdx.x;
  const int wv = tid >> 6, lane = tid & 63, m = lane & 15, q = lane >> 4;
  const int g  = m & 3;                                   // gate of this lane
  const int u  = wv*16 + q*4 + (m >> 2);                  // unit of this lane
  const float* bi = dir ? bB : bF;
  const float sclc = scl[dir] * (1.f/16129.f);            // sw/(127*127)
  // activation constants: gate 2 is tanh = 2*sigmoid(2x)-1 (exact: x2 is lossless)
  const float em = (g==2) ? -2.f : -1.f;
  const float ym = (g==2) ?  2.f :  1.f;
  const float ya = (g==2) ? -1.f :  0.f;
  const float bzl = bi[g*128 + u];

  __shared__ __align__(16) char AbufC[2][128];            // h int8, double-buffered

  // B fragments: tile qt (lane-quarter) -> rows (qt*8+wv)*16 + m
  bf16x8 Bfx[4];
  intx4  BfQ[4][2];
  {
    const ushort_t* Bx = B0X + (size_t)dir*16384;
    const char*     Bq = W0Q + (size_t)dir*65536;
    #pragma unroll
    for (int qt=0; qt<4; qt++){
      int nrow = (qt*8 + wv)*16 + m;
      Bfx[qt] = *(const bf16x8*)(Bx + (size_t)nrow*32 + q*8);
      #pragma unroll
      for (int kt=0; kt<2; kt++)
        BfQ[qt][kt] = *(const intx4*)(Bq + (size_t)nrow*128 + kt*64 + q*16);
    }
  }

  if (tid < 64) ((uint32_t*)AbufC)[tid] = 0u;             // zero both buffers

  // x fragment stream: value depends only on q (16-lane broadcast loads)
  const ushort_t* xap = xA + ((size_t)b*TT*4 + q)*8;
  uint4 px[4];
  #pragma unroll
  for (int j=0; j<4; j++){
    int tj = dir ? (TT-1-j) : j;
    px[j] = *(const uint4*)(xap + (size_t)tj*32);
  }
  const ushort_t* xpp = xap + (size_t)(dir ? (TT-5) : 4)*32;
  const int xstep = dir ? -32 : 32;   // ushorts per step
  __syncthreads();

  const floatx4 z4 = {0.f,0.f,0.f,0.f};
  const intx4  zi = {0,0,0,0};
  float cst = 0.f;
  const int t00 = dir ? TT-1 : 0;
  ushort_t* hp = h0seq + ((size_t)b*TT + t00)*256 + dir*128 + u;
  const int hstep = dir ? -256 : 256;

  for (int i = 0; i < TT/4; ++i){
    #pragma unroll
    for (int p = 0; p < 4; ++p){
      const int s = i*4 + p;
      const int cur = s & 1, nxt = cur ^ 1;

      const char* ar = &AbufC[cur][0];
      intx4 AfQ0 = *(const intx4*)(ar + q*16);
      intx4 AfQ1 = *(const intx4*)(ar + 64 + q*16);
      bf16x8 Ax = *(const bf16x8*)&px[p];

      // 4 independent tile-chains (x bf16 first: register operands cover ds_read)
      floatx4 ax0 = __builtin_amdgcn_mfma_f32_16x16x32_bf16(Ax, Bfx[0], z4, 0,0,0);
      floatx4 ax1 = __builtin_amdgcn_mfma_f32_16x16x32_bf16(Ax, Bfx[1], z4, 0,0,0);
      floatx4 ax2 = __builtin_amdgcn_mfma_f32_16x16x32_bf16(Ax, Bfx[2], z4, 0,0,0);
      floatx4 ax3 = __builtin_amdgcn_mfma_f32_16x16x32_bf16(Ax, Bfx[3], z4, 0,0,0);

      intx4 aq0 = __builtin_amdgcn_mfma_i32_16x16x64_i8(AfQ0, BfQ[0][0], zi, 0,0,0);
      intx4 aq1 = __builtin_amdgcn_mfma_i32_16x16x64_i8(AfQ0, BfQ[1][0], zi, 0,0,0);
      intx4 aq2 = __builtin_amdgcn_mfma_i32_16x16x64_i8(AfQ0, BfQ[2][0], zi, 0,0,0);
      intx4 aq3 = __builtin_amdgcn_mfma_i32_16x16x64_i8(AfQ0, BfQ[3][0], zi, 0,0,0);
      aq0 = __builtin_amdgcn_mfma_i32_16x16x64_i8(AfQ1, BfQ[0][1], aq0, 0,0,0);
      aq1 = __builtin_amdgcn_mfma_i32_16x16x64_i8(AfQ1, BfQ[1][1], aq1, 0,0,0);
      aq2 = __builtin_amdgcn_mfma_i32_16x16x64_i8(AfQ1, BfQ[2][1], aq2, 0,0,0);
      aq3 = __builtin_amdgcn_mfma_i32_16x16x64_i8(AfQ1, BfQ[3][1], aq3, 0,0,0);

      // px reload for step s+4
      px[p] = *(const uint4*)xpp;
      xpp += xstep;

      // select this lane's tile (qt = q): 3 cndmask per operand
      float axs = (q < 2) ? ((q == 0) ? ax0[0] : ax1[0])
                          : ((q == 2) ? ax2[0] : ax3[0]);
      int   aqs = (q < 2) ? ((q == 0) ? aq0[0] : aq1[0])
                          : ((q == 2) ? aq2[0] : aq3[0]);

      {
        float z = (float)aqs*sclc + axs + bzl;
        float e = __expf(z * em);
        float y = 1.f/(1.f + e);
        float act = ym*y + ya;               // sigmoid or tanh (exact)

        int ai = __float_as_int(act);
        float sf = __int_as_float(__builtin_amdgcn_ds_swizzle(ai, 0x041F)); // ^1 -> f
        float sg = __int_as_float(__builtin_amdgcn_ds_swizzle(ai, 0x081F)); // ^2 -> g^
        float so = __int_as_float(__builtin_amdgcn_ds_swizzle(ai, 0x0C1F)); // ^3 -> o

        float cc = sf*cst + act*sg;          // f*c + i*g^   (valid in g==0 lanes)
        cst = cc;
        float hl = so*ftanh(cc);             // o*tanh(c)
        if (g == 0){
          AbufC[nxt][u] = (char)(int)rintf(hl * 127.f);
          *hp = f2bf(hl);                    // fire-and-forget bf16 h
        }
        hp += hstep;
      }
      ldsbar();
    }
  }
}

// ---------------- K2: xz1R[dir][b][t][u(64)][g(4)] = bf16( h0seq[bt][:256] @ Wx1[dir] )
__global__ __launch_bounds__(512) void k_xz1_gemm(const ushort_t* __restrict__ h0seq,
                                                  const ushort_t* __restrict__ WxT,
                                                  ushort_t* __restrict__ xz1)
{
  const int mb  = blockIdx.x;
  const int dir = blockIdx.y;
  const ushort_t* W   = WxT + (size_t)dir*256*256;
  ushort_t*       out = xz1 + (size_t)dir*BB*TT*256;
  const int wave = threadIdx.x >> 6;
  const int lane = threadIdx.x & 63;
  const int mw = wave & 3;
  const int nw = wave >> 2;
  const int m_ = lane & 15;
  const int q_ = lane >> 4;

  floatx4 acc[2][8];
  #pragma unroll
  for (int a=0;a<2;a++)
    #pragma unroll
    for (int n=0;n<8;n++) acc[a][n] = (floatx4)0.f;

  const size_t Abase = ((size_t)mb*128 + mw*32 + m_)*256 + q_*8;
  const size_t Bbase = ((size_t)nw*128 + m_)*256 + q_*8;

  for (int kc = 0; kc < 256; kc += 32){
    bf16x8 afr[2];
    #pragma unroll
    for (int mt=0;mt<2;mt++)
      afr[mt] = *(const bf16x8*)(h0seq + Abase + (size_t)mt*16*256 + kc);
    #pragma unroll
    for (int nt=0;nt<8;nt++){
      bf16x8 bfr = *(const bf16x8*)(W + Bbase + (size_t)nt*16*256 + kc);
      #pragma unroll
      for (int mt=0;mt<2;mt++)
        acc[mt][nt] = __builtin_amdgcn_mfma_f32_16x16x32_bf16(afr[mt], bfr, acc[mt][nt], 0,0,0);
    }
  }
  #pragma unroll
  for (int mt=0;mt<2;mt++)
    #pragma unroll
    for (int r=0;r<4;r++){
      size_t bt = (size_t)mb*128 + mw*32 + mt*16 + q_*4 + r;
      ushort_t* rowp = out + bt*256;
      #pragma unroll
      for (int wvz=0; wvz<4; wvz++){
        uint32_t lo = f2bf(acc[mt][wvz][r]);
        uint32_t hi = f2bf(acc[mt][wvz+4][r]);
        *(uint32_t*)(rowp + (wvz*16+m_)*4 + 2*nw) = lo | (hi << 16);
      }
    }
}

// ---------------- K3: layer-1 scan v8: one chain per WG, 128 WGs, 4 waves.
// Same transform as K1-v7 (r8: +340us on layer 0): each lane owns ONE z value
// (gate g=m&3, unit u=wv*16+q*4+(m>>2)); per-wave MFMA = 4 independent K=64 i8
// (16 n-tiles over 4 waves); gates combined via ds_swizzle xor1/2/3; xz
// prefetch is one coalesced ushort per lane.
__global__ __launch_bounds__(256, 1) void k_lstm1m(
  const ushort_t* __restrict__ xz1R,                // [dir][b][t][u][g] bf16
  const char* __restrict__ W1Q,                     // permuted [dir][row][k=64] int8
  const float* __restrict__ scl,
  const float* __restrict__ bF, const float* __restrict__ bB,
  float* __restrict__ h1last)                       // [B][128]: fwd 0..63, bwd 64..127
{
  const int dir = blockIdx.x & 1, b = blockIdx.x >> 1;    // b 0..63
  const int tid = threadIdx.x;
  const int wv = tid >> 6, lane = tid & 63, m = lane & 15, q = lane >> 4;
  const int g = m & 3;                                    // gate of this lane
  const int u = wv*16 + q*4 + (m >> 2);                   // unit of this lane
  const float* bi = dir ? bB : bF;
  const float sclc = scl[2+dir] * (1.f/16129.f);
  const float em = (g==2) ? -2.f : -1.f;
  const float ym = (g==2) ?  2.f :  1.f;
  const float ya = (g==2) ? -1.f :  0.f;
  const float bzl = bi[g*64 + u];

  __shared__ __align__(16) char HbufC[2][64];             // h int8, double-buffered

  intx4 BfQ[4];                           // tile qt -> row (qt*4+wv)*16 + m
  {
    const char* Bq = W1Q + (size_t)dir*16384;
    #pragma unroll
    for (int qt=0; qt<4; qt++)
      BfQ[qt] = *(const intx4*)(Bq + (size_t)((qt*4 + wv)*16 + m)*64 + q*16);
  }

  if (tid < 32) ((uint32_t*)HbufC)[tid] = 0u;             // zero both buffers

  const ushort_t* xzr = xz1R + ((size_t)dir*BB + b)*TT*256 + (size_t)(u*4 + g);
  ushort_t pz[4];
  #pragma unroll
  for (int j=0; j<4; j++){
    int tj = dir ? (TT-1-j) : j;
    pz[j] = xzr[(size_t)tj*256];
  }
  const ushort_t* xpp = xzr + (size_t)(dir ? (TT-5) : 4)*256;
  const int zstep = dir ? -256 : 256;      // ushorts per step
  __syncthreads();

  const intx4 zi = {0,0,0,0};
  float cst = 0.f, hl = 0.f;

  for (int i = 0; i < TT/4; ++i){
    #pragma unroll
    for (int p = 0; p < 4; ++p){
      const int s = i*4 + p;
      const int cur = s & 1, nxt = cur ^ 1;

      intx4 AfQ = *(const intx4*)(&HbufC[cur][0] + q*16);

      // hoisted xz+bias partial under the ds_read shadow, + stepped reload
      float w = bzl + bf2f(pz[p]);
      pz[p] = *xpp;
      xpp += zstep;

      // 4 independent K=64 i8 MFMAs: all 64 n-columns this wave owns
      intx4 c0 = __builtin_amdgcn_mfma_i32_16x16x64_i8(AfQ, BfQ[0], zi, 0,0,0);
      intx4 c1 = __builtin_amdgcn_mfma_i32_16x16x64_i8(AfQ, BfQ[1], zi, 0,0,0);
      intx4 c2 = __builtin_amdgcn_mfma_i32_16x16x64_i8(AfQ, BfQ[2], zi, 0,0,0);
      intx4 c3 = __builtin_amdgcn_mfma_i32_16x16x64_i8(AfQ, BfQ[3], zi, 0,0,0);

      int aqs = (q < 2) ? ((q == 0) ? c0[0] : c1[0])
                        : ((q == 2) ? c2[0] : c3[0]);

      {
        float z = (float)aqs*sclc + w;
        float e = __expf(z * em);
        float y = 1.f/(1.f + e);
        float act = ym*y + ya;               // sigmoid or tanh (exact)

        int ai = __float_as_int(act);
        float sf = __int_as_float(__builtin_amdgcn_ds_swizzle(ai, 0x041F)); // ^1 -> f
        float sg = __int_as_float(__builtin_amdgcn_ds_swizzle(ai, 0x081F)); // ^2 -> g^
        float so = __int_as_float(__builtin_amdgcn_ds_swizzle(ai, 0x0C1F)); // ^3 -> o

        float cc = sf*cst + act*sg;          // valid in g==0 lanes
        cst = cc;
        hl = so*ftanh(cc);
        if (g == 0) HbufC[nxt][u] = (char)(int)rintf(hl * 127.f);
      }
      ldsbar();
    }
  }
  if (g == 0) h1last[(size_t)b*128 + dir*64 + u] = hl;
}

// ---------------- K4: dense head
__global__ __launch_bounds__(128) void k_head(
  const float* __restrict__ h1last,
  const float* __restrict__ d0W, const float* __restrict__ d0b,
  const float* __restrict__ d1W, const float* __restrict__ d1b,
  const float* __restrict__ oW,  const float* __restrict__ ob,
  float* __restrict__ outp)
{
  const int b = blockIdx.x;
  const int j = threadIdx.x;
  __shared__ float v0[128], v1[128];
  v0[j] = h1last[b*128 + j];
  __syncthreads();
  float acc = d0b[j];
  #pragma unroll
  for (int k=0;k<128;k++) acc += v0[k]*d0W[k*128 + j];
  v1[j] = fmaxf(acc, 0.f);
  __syncthreads();
  if (j < 64){
    float a2 = d1b[j];
    #pragma unroll
    for (int k=0;k<128;k++) a2 += v1[k]*d1W[k*64 + j];
    float p = fmaxf(a2, 0.f) * oW[j];
    #pragma unroll
    for (int off=32; off>0; off>>=1) p += __shfl_down(p, off, 64);
    if (j == 0) outp[b] = 1.f/(1.f + __expf(-(p + ob[0])));
  }
}

extern "C" void kernel_launch(void* const* d_in, const int* in_sizes, int n_in,
                              void* d_out, int out_size, void* d_ws, size_t ws_size,
                              hipStream_t stream)
{
  const float* x     = (const float*)d_in[0];
  const float* l0fWx = (const float*)d_in[1];
  const float* l0fWh = (const float*)d_in[2];
  const float* l0fb  = (const float*)d_in[3];
  const float* l0bWx = (const float*)d_in[4];
  const float* l0bWh = (const float*)d_in[5];
  const float* l0bb  = (const float*)d_in[6];
  const float* l1fWx = (const float*)d_in[7];
  const float* l1fWh = (const float*)d_in[8];
  const float* l1fb  = (const float*)d_in[9];
  const float* l1bWx = (const float*)d_in[10];
  const float* l1bWh = (const float*)d_in[11];
  const float* l1bb  = (const float*)d_in[12];
  const float* d0W = (const float*)d_in[13];
  const float* d0b = (const float*)d_in[14];
  const float* d1W = (const float*)d_in[15];
  const float* d1b = (const float*)d_in[16];
  const float* oW  = (const float*)d_in[17];
  const float* ob  = (const float*)d_in[18];
  float* outp = (float*)d_out;

  char* ws = (char*)d_ws;
  const size_t OFF_XT  = 0;                        // xc: 7,208,960 (slot 7,864,320)
  const size_t OFF_SCL = 7208960ull;               // 16 B (xc slot slack)
  const size_t OFF_H0  = OFF_XT  + 7864320ull;     // 83,886,080
  const size_t OFF_XZ  = OFF_H0  + 83886080ull;    // 167,772,160 (xz1R; xA overlaps head)
  const size_t OFF_XA  = OFF_XZ;                   // xA: 2,621,440 (dead before xz1 written)
  const size_t OFF_WT  = OFF_XZ  + 167772160ull;   // 262,144
  const size_t OFF_B0  = OFF_WT  + 262144ull;      // slot 327,680: W0Q 131,072 + B0X 65,536
  const size_t OFF_B0X = OFF_B0  + 131072ull;
  const size_t OFF_B1  = OFF_B0  + 327680ull;      // slot 65,536: W1Q 32,768
  const size_t OFF_H1  = OFF_B1  + 65536ull;       // 32,768

  ushort_t* xc  = (ushort_t*)(ws + OFF_XT);
  float*    sclp= (float*)(ws + OFF_SCL);
  ushort_t* h0  = (ushort_t*)(ws + OFF_H0);
  ushort_t* xz1 = (ushort_t*)(ws + OFF_XZ);
  ushort_t* xA  = (ushort_t*)(ws + OFF_XA);
  ushort_t* WT  = (ushort_t*)(ws + OFF_WT);
  char*     W0Q = (char*)(ws + OFF_B0);
  ushort_t* B0X = (ushort_t*)(ws + OFF_B0X);
  char*     W1Q = (char*)(ws + OFF_B1);
  float*    h1l = (float*)(ws + OFF_H1);

  hipLaunchKernelGGL(k_convert_x,   dim3(3520), dim3(256), 0, stream, x, xc);
  hipLaunchKernelGGL(k_prep_xa,     dim3(2560), dim3(256), 0, stream, xc, xA);
  hipLaunchKernelGGL(k_wmax,        dim3(4),    dim3(256), 0, stream, l0fWh, l0bWh, l1fWh, l1bWh, sclp);
  hipLaunchKernelGGL(k_prep_l0,     dim3(640),  dim3(256), 0, stream, l0fWx, l0fWh, l0bWx, l0bWh, sclp, W0Q, B0X);
  hipLaunchKernelGGL(k_prep_l1,     dim3(128),  dim3(256), 0, stream, l1fWh, l1bWh, sclp, W1Q);
  hipLaunchKernelGGL(k_prep_wxT,    dim3(512),  dim3(256), 0, stream, l1fWx, l1bWx, WT);
  hipLaunchKernelGGL(k_lstm0m,      dim3(128),  dim3(512), 0, stream, xA, W0Q, B0X, sclp, l0fb, l0bb, h0);
  hipLaunchKernelGGL(k_xz1_gemm,    dim3(1280,2), dim3(512), 0, stream, h0, WT, xz1);
  hipLaunchKernelGGL(k_lstm1m,      dim3(128),  dim3(256), 0, stream, xz1, W1Q, sclp, l1fb, l1bb, h1l);
  hipLaunchKernelGGL(k_head,        dim3(64),   dim3(128), 0, stream,
                     h1l, d0W, d0b, d1W, d1b, oW, ob, outp);
}